// Round 1
// 70.135 us; speedup vs baseline: 1.0350x; 1.0350x over previous
//
#include <hip/hip_runtime.h>

// Problem constants (from reference setup_inputs):
//   b=8, n=1024, m=2048, x_dim=1, Y_DIM=2 -> c=3, Z_DIM=128
constexpr int B  = 8;
constexpr int N  = 1024;
constexpr int M  = 2048;
constexpr int ZD = 128;
constexpr float EPS = 1e-8f;
constexpr float LOG2E = 1.4426950408889634f;

// Structure: block = 256 threads = 4 waves; each wave = 2 groups of 32 lanes;
// each 32-lane group owns ONE output row j (8 rows/block, grid = 2048 =
// exactly one full-occupancy device pass at 8 blocks/CU).
// i-dim (N=1024) is split across the 32 lanes of a group: 32 i's per lane,
// read as 8 float4 LDS chunks -> 24 ds_read_b128 per wave (vs 48 ds_read_b32
// before), and the two groups of a wave read identical addresses (free
// same-address broadcast). Reduction: 5-step shfl_xor butterfly within the
// 32-lane group on 3 vars = 15 DS ops per wave (vs 36 before).
__global__ __launch_bounds__(256, 8) void encoder_fused(
    const float* __restrict__ x,      // (B, N, 1)
    const float* __restrict__ y,      // (B, N, 2)
    const float* __restrict__ t,      // (B, M, 1)
    const float* __restrict__ sigma,  // (3,)
    const float* __restrict__ W,      // (ZD, 3) row-major
    const float* __restrict__ bfc,    // (ZD,)
    float* __restrict__ out)          // (B, M, ZD)
{
    __shared__ __align__(16) float sx[N];
    __shared__ __align__(16) float sy1[N];
    __shared__ __align__(16) float sy2[N];

    const int blk = blockIdx.x;
    const int b   = blk >> 8;          // 256 blocks per batch
    const int jt  = blk & 255;
    const int tid = threadIdx.x;
    const int l32 = tid & 31;          // lane within 32-lane group
    const int grp = tid >> 5;          // 0..7 -> row owned by this group

    // ---- stage x, y (SoA) into LDS with float4 loads ----
    {
        const float4* x4 = reinterpret_cast<const float4*>(x + b * N);
        reinterpret_cast<float4*>(sx)[tid] = x4[tid];      // 256 f4 = 1024 floats

        const float4* y4 = reinterpret_cast<const float4*>(y + (size_t)b * N * 2);
        const float4 v0 = y4[tid];          // y-pairs for i = 2*tid, 2*tid+1
        const float4 v1 = y4[tid + 256];    // y-pairs for i = 2*(tid+256), +1
        *reinterpret_cast<float2*>(&sy1[2 * tid])         = make_float2(v0.x, v0.z);
        *reinterpret_cast<float2*>(&sy2[2 * tid])         = make_float2(v0.y, v0.w);
        *reinterpret_cast<float2*>(&sy1[2 * (tid + 256)]) = make_float2(v1.x, v1.z);
        *reinterpret_cast<float2*>(&sy2[2 * (tid + 256)]) = make_float2(v1.y, v1.w);
    }

    const float s0 = sigma[0], s1 = sigma[1], s2 = sigma[2];
    // q_c = -0.5 * log2(e) * exp(-2*sigma_c):  kernel_c(d) = exp2(d*d*q_c)
    const float q0 = -0.5f * LOG2E * __builtin_amdgcn_exp2f(-2.0f * s0 * LOG2E);
    const float q1 = -0.5f * LOG2E * __builtin_amdgcn_exp2f(-2.0f * s1 * LOG2E);
    const float q2 = -0.5f * LOG2E * __builtin_amdgcn_exp2f(-2.0f * s2 * LOG2E);

    const int   j  = jt * 8 + grp;
    const float tj = t[b * M + j];

    __syncthreads();

    float z0 = 0.f, z1 = 0.f, z2 = 0.f;

    if (s0 == s1 && s1 == s2) {
        // Fast path (actual data has sigma == 0): one exp serves all 3 channels.
#pragma unroll
        for (int c = 0; c < N / 128; ++c) {
            const int i = c * 128 + l32 * 4;
            const float4 xv  = *reinterpret_cast<const float4*>(&sx[i]);
            const float4 y1v = *reinterpret_cast<const float4*>(&sy1[i]);
            const float4 y2v = *reinterpret_cast<const float4*>(&sy2[i]);
            float d, e;
            d = tj - xv.x; e = __builtin_amdgcn_exp2f(d * d * q0);
            z0 += e; z1 = fmaf(y1v.x, e, z1); z2 = fmaf(y2v.x, e, z2);
            d = tj - xv.y; e = __builtin_amdgcn_exp2f(d * d * q0);
            z0 += e; z1 = fmaf(y1v.y, e, z1); z2 = fmaf(y2v.y, e, z2);
            d = tj - xv.z; e = __builtin_amdgcn_exp2f(d * d * q0);
            z0 += e; z1 = fmaf(y1v.z, e, z1); z2 = fmaf(y2v.z, e, z2);
            d = tj - xv.w; e = __builtin_amdgcn_exp2f(d * d * q0);
            z0 += e; z1 = fmaf(y1v.w, e, z1); z2 = fmaf(y2v.w, e, z2);
        }
    } else {
        // General path: per-channel scales.
#pragma unroll
        for (int c = 0; c < N / 128; ++c) {
            const int i = c * 128 + l32 * 4;
            const float4 xv  = *reinterpret_cast<const float4*>(&sx[i]);
            const float4 y1v = *reinterpret_cast<const float4*>(&sy1[i]);
            const float4 y2v = *reinterpret_cast<const float4*>(&sy2[i]);
            float d, d2;
            d = tj - xv.x; d2 = d * d;
            z0 += __builtin_amdgcn_exp2f(d2 * q0);
            z1 = fmaf(y1v.x, __builtin_amdgcn_exp2f(d2 * q1), z1);
            z2 = fmaf(y2v.x, __builtin_amdgcn_exp2f(d2 * q2), z2);
            d = tj - xv.y; d2 = d * d;
            z0 += __builtin_amdgcn_exp2f(d2 * q0);
            z1 = fmaf(y1v.y, __builtin_amdgcn_exp2f(d2 * q1), z1);
            z2 = fmaf(y2v.y, __builtin_amdgcn_exp2f(d2 * q2), z2);
            d = tj - xv.z; d2 = d * d;
            z0 += __builtin_amdgcn_exp2f(d2 * q0);
            z1 = fmaf(y1v.z, __builtin_amdgcn_exp2f(d2 * q1), z1);
            z2 = fmaf(y2v.z, __builtin_amdgcn_exp2f(d2 * q2), z2);
            d = tj - xv.w; d2 = d * d;
            z0 += __builtin_amdgcn_exp2f(d2 * q0);
            z1 = fmaf(y1v.w, __builtin_amdgcn_exp2f(d2 * q1), z1);
            z2 = fmaf(y2v.w, __builtin_amdgcn_exp2f(d2 * q2), z2);
        }
    }

    // 5-step butterfly within the 32-lane group (xor offsets 16..1 never
    // cross a 32-lane boundary). All lanes end with the full row sums.
#pragma unroll
    for (int off = 16; off; off >>= 1) {
        z0 += __shfl_xor(z0, off);
        z1 += __shfl_xor(z1, off);
        z2 += __shfl_xor(z2, off);
    }

    const float inv = 1.0f / (z0 + EPS);
    const float a1 = z1 * inv, a2 = z2 * inv;

    // Epilogue: lane l32 produces outputs k = 4*l32 .. 4*l32+3 for its row.
    // W floats [12*l32, 12*l32+12) as 3 float4 loads; bfc as 1 float4.
    const float4* W4 = reinterpret_cast<const float4*>(W);
    const float4 wa = W4[l32 * 3 + 0];
    const float4 wb = W4[l32 * 3 + 1];
    const float4 wc = W4[l32 * 3 + 2];
    const float4 bf = reinterpret_cast<const float4*>(bfc)[l32];

    float4 o;
    o.x = fmaf(z0, wa.x, fmaf(a1, wa.y, fmaf(a2, wa.z, bf.x)));
    o.y = fmaf(z0, wa.w, fmaf(a1, wb.x, fmaf(a2, wb.y, bf.y)));
    o.z = fmaf(z0, wb.z, fmaf(a1, wb.w, fmaf(a2, wc.x, bf.z)));
    o.w = fmaf(z0, wc.y, fmaf(a1, wc.z, fmaf(a2, wc.w, bf.w)));

    reinterpret_cast<float4*>(out)[(size_t)(b * M + j) * (ZD / 4) + l32] = o;
}

extern "C" void kernel_launch(void* const* d_in, const int* in_sizes, int n_in,
                              void* d_out, int out_size, void* d_ws, size_t ws_size,
                              hipStream_t stream) {
    const float* x     = (const float*)d_in[0];
    const float* y     = (const float*)d_in[1];
    const float* t     = (const float*)d_in[2];
    const float* sigma = (const float*)d_in[3];
    const float* W     = (const float*)d_in[4];
    const float* bfc   = (const float*)d_in[5];
    float* out = (float*)d_out;

    dim3 grid(B * (M / 8));   // 2048 blocks x 256 threads = one full-occupancy pass
    encoder_fused<<<grid, 256, 0, stream>>>(x, y, t, sigma, W, bfc, out);
}